// Round 4
// baseline (783.414 us; speedup 1.0000x reference)
//
#include <hip/hip_runtime.h>
#include <hip/hip_bf16.h>

// ScAgeNet: encoder (3x [GEMM+BN(eval)+ReLU]) + routed per-cell-type head.
// f32 in/out; internal bf16 MFMA with f32 accumulation.
//
// R4: xor-swizzled LDS (kills 1.65e7 bank-conflict cycles), repack fused into
// L0 staging (f32->bf16 cvt in-register), prep kernels merged.

typedef __bf16 bf16_t;
typedef bf16_t bf16x8 __attribute__((ext_vector_type(8)));
typedef float  f32x4  __attribute__((ext_vector_type(4)));

#define MAX_TILES 544
#define T1_LD 136    // head inter-layer LDS stride (128+8)

// ---------------- BN fold (all 3 layers in one launch) ----------------
__global__ __launch_bounds__(256) void prep_bn_all(
    const float* __restrict__ b0, const float* __restrict__ g0, const float* __restrict__ be0,
    const float* __restrict__ m0, const float* __restrict__ v0,
    const float* __restrict__ b1, const float* __restrict__ g1, const float* __restrict__ be1,
    const float* __restrict__ m1, const float* __restrict__ v1,
    const float* __restrict__ b2i, const float* __restrict__ g2, const float* __restrict__ be2,
    const float* __restrict__ m2, const float* __restrict__ v2,
    float* __restrict__ s0, float* __restrict__ o0,
    float* __restrict__ s1, float* __restrict__ o1,
    float* __restrict__ s2, float* __restrict__ o2) {
    const int bid = blockIdx.x, tid = threadIdx.x;
    const float *b, *g, *be, *m, *v;
    float *s, *o;
    int n;
    if (bid < 2)      { b = b0;  g = g0; be = be0; m = m0; v = v0; s = s0; o = o0; n = bid * 256 + tid; }
    else if (bid == 2){ b = b1;  g = g1; be = be1; m = m1; v = v1; s = s1; o = o1; n = tid; }
    else              { b = b2i; g = g2; be = be2; m = m2; v = v2; s = s2; o = o2; n = tid; }
    float sv = g[n] * rsqrtf(v[n] + 1e-5f);
    s[n] = sv;
    o[n] = (b[n] - m[n]) * sv + be[n];
}

// ---------------- all weight transposes in one launch ----------------
__device__ __forceinline__ void tsp_one(const float* __restrict__ in, bf16_t* __restrict__ out,
                                        const float* __restrict__ scale,
                                        int K, int N, int Kp, unsigned t) {
    const unsigned kchunks = (unsigned)Kp / 8u;
    const unsigned bn = t / kchunks;
    const unsigned kc = t % kchunks;
    const unsigned b  = bn / (unsigned)N;
    const unsigned n  = bn % (unsigned)N;
    const unsigned k0 = kc * 8u;
    const float sc = scale ? scale[n] : 1.f;
    bf16x8 v{};
#pragma unroll
    for (int j = 0; j < 8; ++j) {
        unsigned k = k0 + j;
        v[j] = (k < (unsigned)K) ? (bf16_t)(in[((size_t)b * K + k) * N + n] * sc)
                                 : (bf16_t)0.f;
    }
    *(bf16x8*)&out[((size_t)b * N + n) * Kp + k0] = v;
}

__global__ __launch_bounds__(256) void prep_weights(
    const float* __restrict__ W0, const float* __restrict__ W1, const float* __restrict__ W2,
    const float* __restrict__ HW1, const float* __restrict__ HW2,
    const float* __restrict__ s0, const float* __restrict__ s1, const float* __restrict__ s2,
    bf16_t* __restrict__ Wt0, bf16_t* __restrict__ Wt1, bf16_t* __restrict__ Wt2,
    bf16_t* __restrict__ HW1t, bf16_t* __restrict__ HW2t) {
    unsigned t = blockIdx.x * 256u + threadIdx.x;      // 302080 threads exactly
    if      (t < 129024u) tsp_one(W0,  Wt0,  s0, 1985, 512, 2016, t);
    else if (t < 145408u) tsp_one(W1,  Wt1,  s1, 512,  256, 512,  t - 129024u);
    else if (t < 153600u) tsp_one(W2,  Wt2,  s2, 256,  256, 256,  t - 145408u);
    else if (t < 272384u) tsp_one(HW1, HW1t, nullptr, 256, 128, 256, t - 153600u);
    else                  tsp_one(HW2, HW2t, nullptr, 128, 64,  128, t - 272384u);
}

// ---------------- fused GEMM + bias + ReLU (MFMA 16x16x32, 128x128 tile) ----------------
// AF32: A is f32 [M][KA] (converted to bf16 during staging, masked k-tail);
// else: A is bf16 [M][K]. Bt: bf16 [N][K] (K = padded stride). LDS xor-swizzle:
// chunk (row, j) stored at row*32 + ((j ^ (row&3))*8); reads use quad^(tq&3).
template<bool AF32>
__global__ __launch_bounds__(256) void gemm_bias_relu(const void* __restrict__ Av,
                                                      const bf16_t* __restrict__ Bt,
                                                      const float* __restrict__ bias,
                                                      bf16_t* __restrict__ C,
                                                      int M, int N, int K, int KA) {
    __shared__ bf16_t As[128 * 32];
    __shared__ bf16_t Bs[128 * 32];

    const int tid  = threadIdx.x;
    const int bm0  = blockIdx.y * 128;
    const int bn0  = blockIdx.x * 128;
    const int wave = tid >> 6, lane = tid & 63;
    const int wm   = (wave & 1) * 64, wn = (wave >> 1) * 64;
    const int quad = lane >> 4, tq = lane & 15;
    const int xq   = (quad ^ (tq & 3)) << 3;   // lane-constant read swizzle

    f32x4 acc[4][4] = {};

    const int r0 = tid >> 2;
    const int j0 = tid & 3;
    const int c0 = j0 * 8;
    const int sw = ((j0 ^ (r0 & 3)) << 3);     // write swizzle ((r0+64)&3 == r0&3)

    bf16_t* AsW0 = &As[ r0       * 32 + sw];
    bf16_t* AsW1 = &As[(r0 + 64) * 32 + sw];
    bf16_t* BsW0 = &Bs[ r0       * 32 + sw];
    bf16_t* BsW1 = &Bs[(r0 + 64) * 32 + sw];

    const bf16_t* Ab = (const bf16_t*)Av;
    const float*  Af = (const float*)Av;
    const bf16_t* Bp0 = Bt + (size_t)(bn0 + r0) * K + c0;
    const bf16_t* Bp1 = Bt + (size_t)(bn0 + r0 + 64) * K + c0;

    for (int k0 = 0; k0 < K; k0 += 32) {
        bf16x8 a0, a1;
        if constexpr (AF32) {
            const float* sA0 = Af + (size_t)(bm0 + r0) * KA + k0 + c0;
            const float* sA1 = Af + (size_t)(bm0 + r0 + 64) * KA + k0 + c0;
            if (k0 + 32 <= KA) {
#pragma unroll
                for (int j = 0; j < 8; ++j) { a0[j] = (bf16_t)sA0[j]; a1[j] = (bf16_t)sA1[j]; }
            } else {
#pragma unroll
                for (int j = 0; j < 8; ++j) {
                    bool ok = (k0 + c0 + j) < KA;
                    a0[j] = ok ? (bf16_t)sA0[j] : (bf16_t)0.f;
                    a1[j] = ok ? (bf16_t)sA1[j] : (bf16_t)0.f;
                }
            }
        } else {
            a0 = *(const bf16x8*)(Ab + (size_t)(bm0 + r0) * K + k0 + c0);
            a1 = *(const bf16x8*)(Ab + (size_t)(bm0 + r0 + 64) * K + k0 + c0);
        }
        bf16x8 b0 = *(const bf16x8*)(Bp0 + k0);
        bf16x8 b1 = *(const bf16x8*)(Bp1 + k0);
        __syncthreads();
        *(bf16x8*)AsW0 = a0;
        *(bf16x8*)AsW1 = a1;
        *(bf16x8*)BsW0 = b0;
        *(bf16x8*)BsW1 = b1;
        __syncthreads();

        bf16x8 af[4], bfr[4];
#pragma unroll
        for (int mt = 0; mt < 4; ++mt)
            af[mt] = *(const bf16x8*)&As[(wm + mt * 16 + tq) * 32 + xq];
#pragma unroll
        for (int nt = 0; nt < 4; ++nt)
            bfr[nt] = *(const bf16x8*)&Bs[(wn + nt * 16 + tq) * 32 + xq];
#pragma unroll
        for (int mt = 0; mt < 4; ++mt)
#pragma unroll
            for (int nt = 0; nt < 4; ++nt)
                acc[mt][nt] = __builtin_amdgcn_mfma_f32_16x16x32_bf16(
                    af[mt], bfr[nt], acc[mt][nt], 0, 0, 0);
    }

    // epilogue: D lane mapping col=lane&15, row=(lane>>4)*4+r
#pragma unroll
    for (int nt = 0; nt < 4; ++nt) {
        const int col = bn0 + wn + nt * 16 + tq;
        const float bcol = bias[col];
#pragma unroll
        for (int mt = 0; mt < 4; ++mt) {
#pragma unroll
            for (int r = 0; r < 4; ++r) {
                const int row = bm0 + wm + mt * 16 + quad * 4 + r;
                float v = acc[mt][nt][r] + bcol;
                v = v > 0.f ? v : 0.f;
                C[(size_t)row * N + col] = (bf16_t)v;
            }
        }
    }
}

// ---------------- head bucketing ----------------
__global__ __launch_bounds__(64) void head_init(int* __restrict__ counts) {
    if (threadIdx.x < 32) counts[threadIdx.x] = 0;
}

__global__ __launch_bounds__(256) void head_hist(const int* __restrict__ labels,
                                                 int* __restrict__ counts) {
    __shared__ int h[32];
    if (threadIdx.x < 32) h[threadIdx.x] = 0;
    __syncthreads();
    int c = blockIdx.x * 256 + threadIdx.x;
    atomicAdd(&h[labels[c]], 1);
    __syncthreads();
    if (threadIdx.x < 32) {
        int v = h[threadIdx.x];
        if (v) atomicAdd(&counts[threadIdx.x], v);
    }
}

__global__ __launch_bounds__(1024) void head_plan(const int* __restrict__ counts,
                                                  int* __restrict__ cursor,
                                                  int4* __restrict__ descs) {
    __shared__ int offs[30];
    __shared__ int toffs[30];
    if (threadIdx.x == 0) {
        int off = 0, toff = 0;
        for (int e = 0; e < 29; ++e) {
            offs[e] = off; toffs[e] = toff;
            int n = counts[e];
            off += n; toff += (n + 63) >> 6;
        }
        offs[29] = off; toffs[29] = toff;
    }
    __syncthreads();
    if (threadIdx.x < 29) cursor[threadIdx.x] = offs[threadIdx.x];
    int t = threadIdx.x;
    if (t < MAX_TILES) {
        int4 d = make_int4(0, 0, 0, 0);
        if (t < toffs[29]) {
            int e = 0;
            while (toffs[e + 1] <= t) ++e;
            int ti = t - toffs[e];
            int n  = counts[e];
            d.x = e;
            d.y = offs[e] + ti * 64;
            d.z = min(64, n - ti * 64);
        }
        descs[t] = d;
    }
}

__global__ __launch_bounds__(256) void head_scatter(const int* __restrict__ labels,
                                                    int* __restrict__ cursor,
                                                    int* __restrict__ perm) {
    int c = blockIdx.x * 256 + threadIdx.x;
    int p = atomicAdd(&cursor[labels[c]], 1);
    perm[p] = c;
}

// ---------------- MFMA head: one block per 64-cell tile of one expert ----------------
__global__ __launch_bounds__(256) void head_mfma(const bf16_t* __restrict__ feats,
                                                 const int* __restrict__ perm,
                                                 const int4* __restrict__ descs,
                                                 const bf16_t* __restrict__ HW1t,
                                                 const float* __restrict__ Hb1,
                                                 const float* __restrict__ LG1,
                                                 const float* __restrict__ LB1,
                                                 const bf16_t* __restrict__ HW2t,
                                                 const float* __restrict__ Hb2,
                                                 const float* __restrict__ LG2,
                                                 const float* __restrict__ LB2,
                                                 const float* __restrict__ HWo,
                                                 const float* __restrict__ Hbo,
                                                 float* __restrict__ out) {
    __shared__ bf16_t t1s[64 * T1_LD];

    const int4 d = descs[blockIdx.x];
    const int e = d.x, start = d.y, count = d.z;
    if (count == 0) return;

    const int tid = threadIdx.x, w = tid >> 6, lane = tid & 63;
    const int tq = lane & 15, quad = lane >> 4;
    const int m0 = w * 16;

    const int am = m0 + tq;
    const int ridx = perm[start + ((am < count) ? am : 0)];
    const bf16_t* arow = feats + (size_t)ridx * 256;

    // ---- layer 1: [16 x 256] @ [256 x 128] ----
    const bf16_t* w1 = HW1t + (size_t)e * 128 * 256;
    f32x4 acc1[8] = {};
#pragma unroll
    for (int ks = 0; ks < 8; ++ks) {
        bf16x8 a = *(const bf16x8*)(arow + ks * 32 + quad * 8);
#pragma unroll
        for (int nt = 0; nt < 8; ++nt) {
            bf16x8 b = *(const bf16x8*)(w1 + (size_t)(nt * 16 + tq) * 256 + ks * 32 + quad * 8);
            acc1[nt] = __builtin_amdgcn_mfma_f32_16x16x32_bf16(a, b, acc1[nt], 0, 0, 0);
        }
    }

    float s1[4] = {}, q1[4] = {};
#pragma unroll
    for (int nt = 0; nt < 8; ++nt) {
        float hb = Hb1[e * 128 + nt * 16 + tq];
#pragma unroll
        for (int r = 0; r < 4; ++r) {
            float v = acc1[nt][r] + hb;
            acc1[nt][r] = v;
            s1[r] += v; q1[r] += v * v;
        }
    }
#pragma unroll
    for (int off = 1; off < 16; off <<= 1)
#pragma unroll
        for (int r = 0; r < 4; ++r) {
            s1[r] += __shfl_xor(s1[r], off);
            q1[r] += __shfl_xor(q1[r], off);
        }
    float mu1[4], rs1[4];
#pragma unroll
    for (int r = 0; r < 4; ++r) {
        mu1[r] = s1[r] * (1.f / 128.f);
        rs1[r] = rsqrtf(q1[r] * (1.f / 128.f) - mu1[r] * mu1[r] + 1e-5f);
    }
#pragma unroll
    for (int nt = 0; nt < 8; ++nt) {
        const int col = nt * 16 + tq;
        const float lg = LG1[e * 128 + col], lb = LB1[e * 128 + col];
#pragma unroll
        for (int r = 0; r < 4; ++r) {
            float t = (acc1[nt][r] - mu1[r]) * rs1[r] * lg + lb;
            t1s[(m0 + quad * 4 + r) * T1_LD + col] = (bf16_t)fmaxf(t, 0.f);
        }
    }
    __syncthreads();

    // ---- layer 2: [16 x 128] @ [128 x 64] ----
    const bf16_t* w2 = HW2t + (size_t)e * 64 * 128;
    f32x4 acc2[4] = {};
#pragma unroll
    for (int ks = 0; ks < 4; ++ks) {
        bf16x8 a = *(const bf16x8*)&t1s[(m0 + tq) * T1_LD + ks * 32 + quad * 8];
#pragma unroll
        for (int nt = 0; nt < 4; ++nt) {
            bf16x8 b = *(const bf16x8*)(w2 + (size_t)(nt * 16 + tq) * 128 + ks * 32 + quad * 8);
            acc2[nt] = __builtin_amdgcn_mfma_f32_16x16x32_bf16(a, b, acc2[nt], 0, 0, 0);
        }
    }

    float s2[4] = {}, q2[4] = {};
#pragma unroll
    for (int nt = 0; nt < 4; ++nt) {
        float hb = Hb2[e * 64 + nt * 16 + tq];
#pragma unroll
        for (int r = 0; r < 4; ++r) {
            float v = acc2[nt][r] + hb;
            acc2[nt][r] = v;
            s2[r] += v; q2[r] += v * v;
        }
    }
#pragma unroll
    for (int off = 1; off < 16; off <<= 1)
#pragma unroll
        for (int r = 0; r < 4; ++r) {
            s2[r] += __shfl_xor(s2[r], off);
            q2[r] += __shfl_xor(q2[r], off);
        }
    float p[4] = {};
#pragma unroll
    for (int nt = 0; nt < 4; ++nt) {
        const int col = nt * 16 + tq;
        const float lg = LG2[e * 64 + col], lb = LB2[e * 64 + col];
        const float wo = HWo[e * 64 + col];
#pragma unroll
        for (int r = 0; r < 4; ++r) {
            float mu = s2[r] * (1.f / 64.f);
            float rs = rsqrtf(q2[r] * (1.f / 64.f) - mu * mu + 1e-5f);
            float t = (acc2[nt][r] - mu) * rs * lg + lb;
            p[r] += fmaxf(t, 0.f) * wo;
        }
    }
#pragma unroll
    for (int off = 1; off < 16; off <<= 1)
#pragma unroll
        for (int r = 0; r < 4; ++r) p[r] += __shfl_xor(p[r], off);

    if (tq == 0) {
        const float hbo = Hbo[e];
#pragma unroll
        for (int r = 0; r < 4; ++r) {
            int m = m0 + quad * 4 + r;
            if (m < count) out[perm[start + m]] = p[r] + hbo;
        }
    }
}

// ---------------- workspace layout (bytes) ----------------
static const size_t OFF_H0    = 0;                  // 33,554,432
static const size_t OFF_H1    = 33554432;           // 16,777,216
static const size_t OFF_FEATS = 50331648;           // 16,777,216
static const size_t OFF_WT0   = 67108864;           // 2,064,384
static const size_t OFF_WT1   = 69173248;           // 262,144
static const size_t OFF_WT2   = 69435392;           // 131,072
static const size_t OFF_HW1T  = 69566464;           // 1,900,544
static const size_t OFF_HW2T  = 71467008;           // 475,136
static const size_t OFF_B20   = 71942144;
static const size_t OFF_B21   = 71944192;
static const size_t OFF_B22   = 71945216;
static const size_t OFF_S0    = 71946240;
static const size_t OFF_S1    = 71948288;
static const size_t OFF_S2    = 71949312;
static const size_t OFF_CNT   = 71950336;
static const size_t OFF_CUR   = 71950464;
static const size_t OFF_DESC  = 71950592;
static const size_t OFF_PERM  = 71959296;           // 131,072  -> end ~72.1 MB

extern "C" void kernel_launch(void* const* d_in, const int* in_sizes, int n_in,
                              void* d_out, int out_size, void* d_ws, size_t ws_size,
                              hipStream_t stream) {
    const float* x      = (const float*)d_in[0];
    const int*   labels = (const int*)d_in[1];
    const float* W[3]   = {(const float*)d_in[2], (const float*)d_in[8],  (const float*)d_in[14]};
    const float* bb[3]  = {(const float*)d_in[3], (const float*)d_in[9],  (const float*)d_in[15]};
    const float* g[3]   = {(const float*)d_in[4], (const float*)d_in[10], (const float*)d_in[16]};
    const float* be[3]  = {(const float*)d_in[5], (const float*)d_in[11], (const float*)d_in[17]};
    const float* mm[3]  = {(const float*)d_in[6], (const float*)d_in[12], (const float*)d_in[18]};
    const float* vv[3]  = {(const float*)d_in[7], (const float*)d_in[13], (const float*)d_in[19]};
    const float* HW1 = (const float*)d_in[20];
    const float* Hb1 = (const float*)d_in[21];
    const float* LG1 = (const float*)d_in[22];
    const float* LB1 = (const float*)d_in[23];
    const float* HW2 = (const float*)d_in[24];
    const float* Hb2 = (const float*)d_in[25];
    const float* LG2 = (const float*)d_in[26];
    const float* LB2 = (const float*)d_in[27];
    const float* HWo = (const float*)d_in[28];
    const float* Hbo = (const float*)d_in[29];

    char* ws = (char*)d_ws;
    bf16_t* h0    = (bf16_t*)(ws + OFF_H0);
    bf16_t* h1    = (bf16_t*)(ws + OFF_H1);
    bf16_t* feats = (bf16_t*)(ws + OFF_FEATS);
    bf16_t* Wt0   = (bf16_t*)(ws + OFF_WT0);
    bf16_t* Wt1   = (bf16_t*)(ws + OFF_WT1);
    bf16_t* Wt2   = (bf16_t*)(ws + OFF_WT2);
    bf16_t* HW1t  = (bf16_t*)(ws + OFF_HW1T);
    bf16_t* HW2t  = (bf16_t*)(ws + OFF_HW2T);
    float*  b20   = (float*)(ws + OFF_B20);
    float*  b21   = (float*)(ws + OFF_B21);
    float*  b22   = (float*)(ws + OFF_B22);
    float*  s0    = (float*)(ws + OFF_S0);
    float*  s1    = (float*)(ws + OFF_S1);
    float*  s2    = (float*)(ws + OFF_S2);
    int*    cnt   = (int*)(ws + OFF_CNT);
    int*    cur   = (int*)(ws + OFF_CUR);
    int4*   descs = (int4*)(ws + OFF_DESC);
    int*    perm  = (int*)(ws + OFF_PERM);
    float*  outp  = (float*)d_out;

    // 1) BN fold + all weight transposes
    prep_bn_all<<<4, 256, 0, stream>>>(bb[0], g[0], be[0], mm[0], vv[0],
                                       bb[1], g[1], be[1], mm[1], vv[1],
                                       bb[2], g[2], be[2], mm[2], vv[2],
                                       s0, b20, s1, b21, s2, b22);
    prep_weights<<<1180, 256, 0, stream>>>(W[0], W[1], W[2], HW1, HW2,
                                           s0, s1, s2, Wt0, Wt1, Wt2, HW1t, HW2t);

    // 2) bucketing (independent of encoder; only needs labels)
    head_init<<<1, 64, 0, stream>>>(cnt);
    head_hist<<<128, 256, 0, stream>>>(labels, cnt);
    head_plan<<<1, 1024, 0, stream>>>(cnt, cur, descs);
    head_scatter<<<128, 256, 0, stream>>>(labels, cur, perm);

    // 3) encoder GEMMs (L0 reads f32 x directly, cvt in staging, masked K-tail)
    dim3 blk(256);
    dim3 grid0(512 / 128, 32768 / 128);
    gemm_bias_relu<true><<<grid0, blk, 0, stream>>>(x, Wt0, b20, h0, 32768, 512, 2016, 1985);
    dim3 grid1(256 / 128, 32768 / 128);
    gemm_bias_relu<false><<<grid1, blk, 0, stream>>>(h0, Wt1, b21, h1, 32768, 256, 512, 512);
    gemm_bias_relu<false><<<grid1, blk, 0, stream>>>(h1, Wt2, b22, feats, 32768, 256, 256, 256);

    // 4) MFMA head over bucketed tiles
    head_mfma<<<MAX_TILES, 256, 0, stream>>>(feats, perm, descs, HW1t, Hb1, LG1, LB1,
                                             HW2t, Hb2, LG2, LB2, HWo, Hbo, outp);
}

// Round 5
// 742.215 us; speedup vs baseline: 1.0555x; 1.0555x over previous
//
#include <hip/hip_runtime.h>
#include <hip/hip_bf16.h>

// ScAgeNet: encoder (3x [GEMM+BN(eval)+ReLU]) + routed per-cell-type head.
// f32 in/out; internal bf16 MFMA with f32 accumulation.
//
// R5: gemms use global_load_lds (16B DMA) staging, natural [128][32] LDS
// layout (uniform bank residue for b128 reads), XCD-grouped block decode so
// the N-tiles of an M-tile share an XCD's L2 (A fetched ~once). Separate
// repack (HBM-ceiling) restores bf16 A for L0.

typedef __bf16 bf16_t;
typedef bf16_t bf16x8 __attribute__((ext_vector_type(8)));
typedef float  f32x4  __attribute__((ext_vector_type(4)));

#define MAX_TILES 544
#define T1_LD 136    // head inter-layer LDS stride (128+8)

__device__ __forceinline__ void gld16(const bf16_t* g, bf16_t* l) {
    __builtin_amdgcn_global_load_lds(
        (const __attribute__((address_space(1))) void*)g,
        (__attribute__((address_space(3))) void*)l,
        16, 0, 0);
}

// ---------------- repack x: f32 [32768][1985] -> bf16 [32768][2016] zero-padded ----------------
__global__ __launch_bounds__(256) void repack_x(const float* __restrict__ x,
                                                bf16_t* __restrict__ xp) {
    const unsigned idx = blockIdx.x * 256u + threadIdx.x;   // 66,060,288 threads exactly
    const unsigned r = idx / 2016u;
    const unsigned c = idx % 2016u;
    float v = (c < 1985u) ? x[(size_t)r * 1985u + c] : 0.f;
    xp[idx] = (bf16_t)v;
}

// ---------------- BN fold (all 3 layers in one launch) ----------------
__global__ __launch_bounds__(256) void prep_bn_all(
    const float* __restrict__ b0, const float* __restrict__ g0, const float* __restrict__ be0,
    const float* __restrict__ m0, const float* __restrict__ v0,
    const float* __restrict__ b1, const float* __restrict__ g1, const float* __restrict__ be1,
    const float* __restrict__ m1, const float* __restrict__ v1,
    const float* __restrict__ b2i, const float* __restrict__ g2, const float* __restrict__ be2,
    const float* __restrict__ m2, const float* __restrict__ v2,
    float* __restrict__ s0, float* __restrict__ o0,
    float* __restrict__ s1, float* __restrict__ o1,
    float* __restrict__ s2, float* __restrict__ o2) {
    const int bid = blockIdx.x, tid = threadIdx.x;
    const float *b, *g, *be, *m, *v;
    float *s, *o;
    int n;
    if (bid < 2)      { b = b0;  g = g0; be = be0; m = m0; v = v0; s = s0; o = o0; n = bid * 256 + tid; }
    else if (bid == 2){ b = b1;  g = g1; be = be1; m = m1; v = v1; s = s1; o = o1; n = tid; }
    else              { b = b2i; g = g2; be = be2; m = m2; v = v2; s = s2; o = o2; n = tid; }
    float sv = g[n] * rsqrtf(v[n] + 1e-5f);
    s[n] = sv;
    o[n] = (b[n] - m[n]) * sv + be[n];
}

// ---------------- all weight transposes in one launch ----------------
__device__ __forceinline__ void tsp_one(const float* __restrict__ in, bf16_t* __restrict__ out,
                                        const float* __restrict__ scale,
                                        int K, int N, int Kp, unsigned t) {
    const unsigned kchunks = (unsigned)Kp / 8u;
    const unsigned bn = t / kchunks;
    const unsigned kc = t % kchunks;
    const unsigned b  = bn / (unsigned)N;
    const unsigned n  = bn % (unsigned)N;
    const unsigned k0 = kc * 8u;
    const float sc = scale ? scale[n] : 1.f;
    bf16x8 v{};
#pragma unroll
    for (int j = 0; j < 8; ++j) {
        unsigned k = k0 + j;
        v[j] = (k < (unsigned)K) ? (bf16_t)(in[((size_t)b * K + k) * N + n] * sc)
                                 : (bf16_t)0.f;
    }
    *(bf16x8*)&out[((size_t)b * N + n) * Kp + k0] = v;
}

__global__ __launch_bounds__(256) void prep_weights(
    const float* __restrict__ W0, const float* __restrict__ W1, const float* __restrict__ W2,
    const float* __restrict__ HW1, const float* __restrict__ HW2,
    const float* __restrict__ s0, const float* __restrict__ s1, const float* __restrict__ s2,
    bf16_t* __restrict__ Wt0, bf16_t* __restrict__ Wt1, bf16_t* __restrict__ Wt2,
    bf16_t* __restrict__ HW1t, bf16_t* __restrict__ HW2t) {
    unsigned t = blockIdx.x * 256u + threadIdx.x;      // 302080 threads exactly
    if      (t < 129024u) tsp_one(W0,  Wt0,  s0, 1985, 512, 2016, t);
    else if (t < 145408u) tsp_one(W1,  Wt1,  s1, 512,  256, 512,  t - 129024u);
    else if (t < 153600u) tsp_one(W2,  Wt2,  s2, 256,  256, 256,  t - 145408u);
    else if (t < 272384u) tsp_one(HW1, HW1t, nullptr, 256, 128, 256, t - 153600u);
    else                  tsp_one(HW2, HW2t, nullptr, 128, 64,  128, t - 272384u);
}

// ---------------- fused GEMM + bias + ReLU (MFMA 16x16x32, 128x128 tile) ----------------
// A: [32768][K] bf16 (K mult of 32, rows 16B-aligned). Bt: [N][K] bf16.
// global_load_lds staging; natural LDS layout [128][32]; XCD-grouped decode.
__global__ __launch_bounds__(256) void gemm_bias_relu(const bf16_t* __restrict__ A,
                                                      const bf16_t* __restrict__ Bt,
                                                      const float* __restrict__ bias,
                                                      bf16_t* __restrict__ C,
                                                      int N, int K, int NT) {
    __shared__ bf16_t As[128 * 32];
    __shared__ bf16_t Bs[128 * 32];

    // blocks with equal (b&7) land on the same XCD (round-robin heuristic);
    // give one M-tile's NT N-tiles the same residue -> A-slab shared in L2.
    const unsigned b = blockIdx.x;
    const unsigned c8 = b & 7u, t = b >> 3;
    const int bn0 = (int)(t % (unsigned)NT) * 128;
    const int bm0 = (int)((t / (unsigned)NT) * 8u + c8) * 128;

    const int tid = threadIdx.x;
    const int wv = tid >> 6, ln = tid & 63;
    const int quad = ln >> 4, tq = ln & 15;
    const int wm = (wv & 1) * 64, wn = (wv >> 1) * 64;

    // DMA staging: wave wv covers rows [wv*16, wv*16+16) and +64 of each tile;
    // lane i -> lds base + i*16B == row (i>>2), col (i&3)*8 (natural layout).
    const int sr = ln >> 2;
    const int sc = (ln & 3) * 8;
    bf16_t* lA0 = &As[(wv * 16) * 32];
    bf16_t* lA1 = &As[(64 + wv * 16) * 32];
    bf16_t* lB0 = &Bs[(wv * 16) * 32];
    bf16_t* lB1 = &Bs[(64 + wv * 16) * 32];
    const bf16_t* gA0 = A + (size_t)(bm0 + wv * 16 + sr) * K + sc;
    const bf16_t* gA1 = A + (size_t)(bm0 + 64 + wv * 16 + sr) * K + sc;
    const bf16_t* gB0 = Bt + (size_t)(bn0 + wv * 16 + sr) * K + sc;
    const bf16_t* gB1 = Bt + (size_t)(bn0 + 64 + wv * 16 + sr) * K + sc;

    f32x4 acc[4][4] = {};

    for (int k0 = 0; k0 < K; k0 += 32) {
        __syncthreads();               // prior iter's LDS reads done
        gld16(gA0 + k0, lA0);
        gld16(gA1 + k0, lA1);
        gld16(gB0 + k0, lB0);
        gld16(gB1 + k0, lB1);
        __syncthreads();               // drains vmcnt -> LDS populated

        bf16x8 af[4], bfr[4];
#pragma unroll
        for (int mt = 0; mt < 4; ++mt)
            af[mt] = *(const bf16x8*)&As[(wm + mt * 16 + tq) * 32 + quad * 8];
#pragma unroll
        for (int nt = 0; nt < 4; ++nt)
            bfr[nt] = *(const bf16x8*)&Bs[(wn + nt * 16 + tq) * 32 + quad * 8];
#pragma unroll
        for (int mt = 0; mt < 4; ++mt)
#pragma unroll
            for (int nt = 0; nt < 4; ++nt)
                acc[mt][nt] = __builtin_amdgcn_mfma_f32_16x16x32_bf16(
                    af[mt], bfr[nt], acc[mt][nt], 0, 0, 0);
    }

    // epilogue: D lane mapping col=lane&15, row=(lane>>4)*4+r
#pragma unroll
    for (int nt = 0; nt < 4; ++nt) {
        const int col = bn0 + wn + nt * 16 + tq;
        const float bcol = bias[col];
#pragma unroll
        for (int mt = 0; mt < 4; ++mt) {
#pragma unroll
            for (int r = 0; r < 4; ++r) {
                const int row = bm0 + wm + mt * 16 + quad * 4 + r;
                float v = acc[mt][nt][r] + bcol;
                v = v > 0.f ? v : 0.f;
                C[(size_t)row * N + col] = (bf16_t)v;
            }
        }
    }
}

// ---------------- head bucketing ----------------
__global__ __launch_bounds__(64) void head_init(int* __restrict__ counts) {
    if (threadIdx.x < 32) counts[threadIdx.x] = 0;
}

__global__ __launch_bounds__(256) void head_hist(const int* __restrict__ labels,
                                                 int* __restrict__ counts) {
    __shared__ int h[32];
    if (threadIdx.x < 32) h[threadIdx.x] = 0;
    __syncthreads();
    int c = blockIdx.x * 256 + threadIdx.x;
    atomicAdd(&h[labels[c]], 1);
    __syncthreads();
    if (threadIdx.x < 32) {
        int v = h[threadIdx.x];
        if (v) atomicAdd(&counts[threadIdx.x], v);
    }
}

__global__ __launch_bounds__(1024) void head_plan(const int* __restrict__ counts,
                                                  int* __restrict__ cursor,
                                                  int4* __restrict__ descs) {
    __shared__ int offs[30];
    __shared__ int toffs[30];
    if (threadIdx.x == 0) {
        int off = 0, toff = 0;
        for (int e = 0; e < 29; ++e) {
            offs[e] = off; toffs[e] = toff;
            int n = counts[e];
            off += n; toff += (n + 63) >> 6;
        }
        offs[29] = off; toffs[29] = toff;
    }
    __syncthreads();
    if (threadIdx.x < 29) cursor[threadIdx.x] = offs[threadIdx.x];
    int t = threadIdx.x;
    if (t < MAX_TILES) {
        int4 d = make_int4(0, 0, 0, 0);
        if (t < toffs[29]) {
            int e = 0;
            while (toffs[e + 1] <= t) ++e;
            int ti = t - toffs[e];
            int n  = counts[e];
            d.x = e;
            d.y = offs[e] + ti * 64;
            d.z = min(64, n - ti * 64);
        }
        descs[t] = d;
    }
}

__global__ __launch_bounds__(256) void head_scatter(const int* __restrict__ labels,
                                                    int* __restrict__ cursor,
                                                    int* __restrict__ perm) {
    int c = blockIdx.x * 256 + threadIdx.x;
    int p = atomicAdd(&cursor[labels[c]], 1);
    perm[p] = c;
}

// ---------------- MFMA head: one block per 64-cell tile of one expert ----------------
__global__ __launch_bounds__(256) void head_mfma(const bf16_t* __restrict__ feats,
                                                 const int* __restrict__ perm,
                                                 const int4* __restrict__ descs,
                                                 const bf16_t* __restrict__ HW1t,
                                                 const float* __restrict__ Hb1,
                                                 const float* __restrict__ LG1,
                                                 const float* __restrict__ LB1,
                                                 const bf16_t* __restrict__ HW2t,
                                                 const float* __restrict__ Hb2,
                                                 const float* __restrict__ LG2,
                                                 const float* __restrict__ LB2,
                                                 const float* __restrict__ HWo,
                                                 const float* __restrict__ Hbo,
                                                 float* __restrict__ out) {
    __shared__ bf16_t t1s[64 * T1_LD];

    const int4 d = descs[blockIdx.x];
    const int e = d.x, start = d.y, count = d.z;
    if (count == 0) return;

    const int tid = threadIdx.x, w = tid >> 6, lane = tid & 63;
    const int tq = lane & 15, quad = lane >> 4;
    const int m0 = w * 16;

    const int am = m0 + tq;
    const int ridx = perm[start + ((am < count) ? am : 0)];
    const bf16_t* arow = feats + (size_t)ridx * 256;

    // ---- layer 1: [16 x 256] @ [256 x 128] ----
    const bf16_t* w1 = HW1t + (size_t)e * 128 * 256;
    f32x4 acc1[8] = {};
#pragma unroll
    for (int ks = 0; ks < 8; ++ks) {
        bf16x8 a = *(const bf16x8*)(arow + ks * 32 + quad * 8);
#pragma unroll
        for (int nt = 0; nt < 8; ++nt) {
            bf16x8 b = *(const bf16x8*)(w1 + (size_t)(nt * 16 + tq) * 256 + ks * 32 + quad * 8);
            acc1[nt] = __builtin_amdgcn_mfma_f32_16x16x32_bf16(a, b, acc1[nt], 0, 0, 0);
        }
    }

    float s1[4] = {}, q1[4] = {};
#pragma unroll
    for (int nt = 0; nt < 8; ++nt) {
        float hb = Hb1[e * 128 + nt * 16 + tq];
#pragma unroll
        for (int r = 0; r < 4; ++r) {
            float v = acc1[nt][r] + hb;
            acc1[nt][r] = v;
            s1[r] += v; q1[r] += v * v;
        }
    }
#pragma unroll
    for (int off = 1; off < 16; off <<= 1)
#pragma unroll
        for (int r = 0; r < 4; ++r) {
            s1[r] += __shfl_xor(s1[r], off);
            q1[r] += __shfl_xor(q1[r], off);
        }
    float mu1[4], rs1[4];
#pragma unroll
    for (int r = 0; r < 4; ++r) {
        mu1[r] = s1[r] * (1.f / 128.f);
        rs1[r] = rsqrtf(q1[r] * (1.f / 128.f) - mu1[r] * mu1[r] + 1e-5f);
    }
#pragma unroll
    for (int nt = 0; nt < 8; ++nt) {
        const int col = nt * 16 + tq;
        const float lg = LG1[e * 128 + col], lb = LB1[e * 128 + col];
#pragma unroll
        for (int r = 0; r < 4; ++r) {
            float tv = (acc1[nt][r] - mu1[r]) * rs1[r] * lg + lb;
            t1s[(m0 + quad * 4 + r) * T1_LD + col] = (bf16_t)fmaxf(tv, 0.f);
        }
    }
    __syncthreads();

    // ---- layer 2: [16 x 128] @ [128 x 64] ----
    const bf16_t* w2 = HW2t + (size_t)e * 64 * 128;
    f32x4 acc2[4] = {};
#pragma unroll
    for (int ks = 0; ks < 4; ++ks) {
        bf16x8 a = *(const bf16x8*)&t1s[(m0 + tq) * T1_LD + ks * 32 + quad * 8];
#pragma unroll
        for (int nt = 0; nt < 4; ++nt) {
            bf16x8 b = *(const bf16x8*)(w2 + (size_t)(nt * 16 + tq) * 128 + ks * 32 + quad * 8);
            acc2[nt] = __builtin_amdgcn_mfma_f32_16x16x32_bf16(a, b, acc2[nt], 0, 0, 0);
        }
    }

    float s2[4] = {}, q2[4] = {};
#pragma unroll
    for (int nt = 0; nt < 4; ++nt) {
        float hb = Hb2[e * 64 + nt * 16 + tq];
#pragma unroll
        for (int r = 0; r < 4; ++r) {
            float v = acc2[nt][r] + hb;
            acc2[nt][r] = v;
            s2[r] += v; q2[r] += v * v;
        }
    }
#pragma unroll
    for (int off = 1; off < 16; off <<= 1)
#pragma unroll
        for (int r = 0; r < 4; ++r) {
            s2[r] += __shfl_xor(s2[r], off);
            q2[r] += __shfl_xor(q2[r], off);
        }
    float p[4] = {};
#pragma unroll
    for (int nt = 0; nt < 4; ++nt) {
        const int col = nt * 16 + tq;
        const float lg = LG2[e * 64 + col], lb = LB2[e * 64 + col];
        const float wo = HWo[e * 64 + col];
#pragma unroll
        for (int r = 0; r < 4; ++r) {
            float mu = s2[r] * (1.f / 64.f);
            float rs = rsqrtf(q2[r] * (1.f / 64.f) - mu * mu + 1e-5f);
            float tv = (acc2[nt][r] - mu) * rs * lg + lb;
            p[r] += fmaxf(tv, 0.f) * wo;
        }
    }
#pragma unroll
    for (int off = 1; off < 16; off <<= 1)
#pragma unroll
        for (int r = 0; r < 4; ++r) p[r] += __shfl_xor(p[r], off);

    if (tq == 0) {
        const float hbo = Hbo[e];
#pragma unroll
        for (int r = 0; r < 4; ++r) {
            int m = m0 + quad * 4 + r;
            if (m < count) out[perm[start + m]] = p[r] + hbo;
        }
    }
}

// ---------------- workspace layout (bytes) — proven <=170.6 MB footprint ----------------
static const size_t OFF_XP    = 0;                  // 132,120,576 (dead after gemm0)
static const size_t OFF_H1    = 0;                  // h1 reuses xp space
static const size_t OFF_FEATS = 16777216;
static const size_t OFF_H0    = 132120576;          // 33,554,432 (dead after gemm1 -> sort structs)
static const size_t OFF_CNT   = 132120576;
static const size_t OFF_CUR   = 132120832;
static const size_t OFF_DESC  = 132121088;
static const size_t OFF_PERM  = 132136960;
static const size_t OFF_WT0   = 165675008;          // 2,064,384
static const size_t OFF_WT1   = 167739392;
static const size_t OFF_WT2   = 168001536;
static const size_t OFF_B20   = 168132608;
static const size_t OFF_B21   = 168134656;
static const size_t OFF_B22   = 168135680;
static const size_t OFF_S0    = 168136704;
static const size_t OFF_S1    = 168138752;
static const size_t OFF_S2    = 168139776;
static const size_t OFF_HW1T  = 168140800;          // 1,900,544
static const size_t OFF_HW2T  = 170041344;          // 475,136

extern "C" void kernel_launch(void* const* d_in, const int* in_sizes, int n_in,
                              void* d_out, int out_size, void* d_ws, size_t ws_size,
                              hipStream_t stream) {
    const float* x      = (const float*)d_in[0];
    const int*   labels = (const int*)d_in[1];
    const float* W[3]   = {(const float*)d_in[2], (const float*)d_in[8],  (const float*)d_in[14]};
    const float* bb[3]  = {(const float*)d_in[3], (const float*)d_in[9],  (const float*)d_in[15]};
    const float* g[3]   = {(const float*)d_in[4], (const float*)d_in[10], (const float*)d_in[16]};
    const float* be[3]  = {(const float*)d_in[5], (const float*)d_in[11], (const float*)d_in[17]};
    const float* mm[3]  = {(const float*)d_in[6], (const float*)d_in[12], (const float*)d_in[18]};
    const float* vv[3]  = {(const float*)d_in[7], (const float*)d_in[13], (const float*)d_in[19]};
    const float* HW1 = (const float*)d_in[20];
    const float* Hb1 = (const float*)d_in[21];
    const float* LG1 = (const float*)d_in[22];
    const float* LB1 = (const float*)d_in[23];
    const float* HW2 = (const float*)d_in[24];
    const float* Hb2 = (const float*)d_in[25];
    const float* LG2 = (const float*)d_in[26];
    const float* LB2 = (const float*)d_in[27];
    const float* HWo = (const float*)d_in[28];
    const float* Hbo = (const float*)d_in[29];

    char* ws = (char*)d_ws;
    bf16_t* xp    = (bf16_t*)(ws + OFF_XP);
    bf16_t* h0    = (bf16_t*)(ws + OFF_H0);
    bf16_t* h1    = (bf16_t*)(ws + OFF_H1);
    bf16_t* feats = (bf16_t*)(ws + OFF_FEATS);
    bf16_t* Wt0   = (bf16_t*)(ws + OFF_WT0);
    bf16_t* Wt1   = (bf16_t*)(ws + OFF_WT1);
    bf16_t* Wt2   = (bf16_t*)(ws + OFF_WT2);
    bf16_t* HW1t  = (bf16_t*)(ws + OFF_HW1T);
    bf16_t* HW2t  = (bf16_t*)(ws + OFF_HW2T);
    float*  b20   = (float*)(ws + OFF_B20);
    float*  b21   = (float*)(ws + OFF_B21);
    float*  b22   = (float*)(ws + OFF_B22);
    float*  s0    = (float*)(ws + OFF_S0);
    float*  s1    = (float*)(ws + OFF_S1);
    float*  s2    = (float*)(ws + OFF_S2);
    int*    cnt   = (int*)(ws + OFF_CNT);
    int*    cur   = (int*)(ws + OFF_CUR);
    int4*   descs = (int4*)(ws + OFF_DESC);
    int*    perm  = (int*)(ws + OFF_PERM);
    float*  outp  = (float*)d_out;

    // 1) prep: BN fold, weight transposes, x repack (all independent)
    prep_bn_all<<<4, 256, 0, stream>>>(bb[0], g[0], be[0], mm[0], vv[0],
                                       bb[1], g[1], be[1], mm[1], vv[1],
                                       bb[2], g[2], be[2], mm[2], vv[2],
                                       s0, b20, s1, b21, s2, b22);
    prep_weights<<<1180, 256, 0, stream>>>(W[0], W[1], W[2], HW1, HW2,
                                           s0, s1, s2, Wt0, Wt1, Wt2, HW1t, HW2t);
    repack_x<<<258048, 256, 0, stream>>>(x, xp);

    // 2) encoder GEMMs (global_load_lds staging, XCD-grouped blocks)
    gemm_bias_relu<<<1024, 256, 0, stream>>>(xp, Wt0, b20, h0, 512, 2016, 4);
    gemm_bias_relu<<<512,  256, 0, stream>>>(h0, Wt1, b21, h1, 256, 512, 2);

    // 3) bucketing (h0 dead after gemm1 -> its region holds sort structs)
    head_init<<<1, 64, 0, stream>>>(cnt);
    head_hist<<<128, 256, 0, stream>>>(labels, cnt);
    head_plan<<<1, 1024, 0, stream>>>(cnt, cur, descs);
    head_scatter<<<128, 256, 0, stream>>>(labels, cur, perm);

    gemm_bias_relu<<<512, 256, 0, stream>>>(h1, Wt2, b22, feats, 256, 256, 2);

    // 4) MFMA head over bucketed tiles
    head_mfma<<<MAX_TILES, 256, 0, stream>>>(feats, perm, descs, HW1t, Hb1, LG1, LB1,
                                             HW2t, Hb2, LG2, LB2, HWo, Hbo, outp);
}